// Round 12
// baseline (587.723 us; speedup 1.0000x reference)
//
#include <hip/hip_runtime.h>
#include <hip/hip_bf16.h>

// AutoregressiveRoutingHead: B=65536, L=8, LATENT=256, HID=128, NTOK=5
//  K1: G[tok][j] = (emb@W_ih + b_ih (+b_hh)) * scale  (exp2-prescaled, 6x768)
//  K2: augmented W -> bf16 frag-linear Wg (16x16x32 A-frags), r10 layout:
//      slice w (cols 16w..+16): f=g*8+kc (g<3,kc<8) = W_hh*scale_g;
//      f=24+g = one-hot K-block (i_r,i_z,bhn,i_n in cols 0..5).
//  K3 (r12): 512 blocks x 512 threads (8 waves, 2/SIMD -> 256-reg cap).
//      Block owns 128 rows as TWO independent 64-row groups:
//      P = waves 0-3 / tiles 0-3, Q = waves 4-7 / tiles 4-7 (one P + one Q
//      wave per SIMD). Groups run half a step apart: each phase, one group
//      streams W+MFMAs while the other combines -> L2 stream overlaps the
//      transcendental VALU across waves of the same SIMD. 17 phases, one
//      lgkm-only barrier each (same count for both groups). h bf16 in LDS,
//      SINGLE-buffered (group reads/writes in different phases). acc =
//      3 gates x 4 col-tiles x 4 row-tiles x f32x4 = 192 regs. One-hot +
//      i_n MFMAs run in the combine phase (transient acc3); oh-frags built
//      in-register from tok. Logits via MFMA during the MFMA phase (skewed).

typedef __attribute__((ext_vector_type(8)))  __bf16 bf16x8;
typedef __attribute__((ext_vector_type(4)))  __bf16 bf16x4;
typedef __attribute__((ext_vector_type(8)))  unsigned short u16x8;
typedef __attribute__((ext_vector_type(4)))  float  f32x4;

#define LOG2E_F     1.4426950408889634f
#define TWO_LOG2E_F 2.8853900817779268f

#if __has_builtin(__builtin_amdgcn_exp2f)
#define EXP2F(x) __builtin_amdgcn_exp2f(x)
#else
#define EXP2F(x) __expf((x) * 0.6931471805599453f)
#endif

__device__ __forceinline__ float sigm2(float a) {   // sigmoid, arg pre-scaled by log2e
    return __builtin_amdgcn_rcpf(1.f + EXP2F(-a));
}
__device__ __forceinline__ float tanh2(float a) {   // tanh, arg pre-scaled by 2log2e
    return __builtin_fmaf(2.f, __builtin_amdgcn_rcpf(1.f + EXP2F(-a)), -1.f);
}
__device__ __forceinline__ void lds_barrier() {
    __builtin_amdgcn_sched_barrier(0);
    asm volatile("s_waitcnt lgkmcnt(0)" ::: "memory");
    __builtin_amdgcn_s_barrier();
    __builtin_amdgcn_sched_barrier(0);
}

#define MFMA16(a, b, c) __builtin_amdgcn_mfma_f32_16x16x32_bf16((a), (b), (c), 0, 0, 0)

// ---------------- K1: gi table (exp2-pre-scaled) ----------------
__global__ void k_gtable(const float* __restrict__ emb, const float* __restrict__ W_ih,
                         const float* __restrict__ b_ih, const float* __restrict__ b_hh,
                         float* __restrict__ G) {
    int tok = blockIdx.x;      // 0..5
    int j   = threadIdx.x;     // 0..767
    const float4* e4 = (const float4*)(emb + tok * 128);
    const float4* w4 = (const float4*)(W_ih + (size_t)j * 128);
    float s = 0.f;
#pragma unroll
    for (int k = 0; k < 32; ++k) {
        float4 a = e4[k], b = w4[k];
        s += a.x * b.x + a.y * b.y + a.z * b.z + a.w * b.w;
    }
    s += b_ih[j];
    if (j < 512) s = (s + b_hh[j]) * LOG2E_F;   // r,z rows
    else         s = s * TWO_LOG2E_F;           // i_n rows
    G[tok * 768 + j] = s;
}

// ---------------- K2: augmented W -> 16x16x32 A-frags (pre-scaled) --------
__global__ void k_wfrag3(const float* __restrict__ Whh, const float* __restrict__ Gtab,
                         const float* __restrict__ b_hh, __bf16* __restrict__ Wg) {
    int u    = blockIdx.x * 256 + threadIdx.x;   // 0..28671 (448 frags x 64 lanes)
    int lane = u & 63;
    int frag = u >> 6;            // 0..447
    int w    = frag / 28;
    int f    = frag - 28 * w;     // 0..27
    int col  = w * 16 + (lane & 15);
    int kq   = lane >> 4;
    bf16x8 v;
    if (f < 24) {
        int g = f >> 3, kc = f & 7;
        float scale = (g < 2) ? LOG2E_F : TWO_LOG2E_F;
        const float* src = Whh + (size_t)(g * 256 + col) * 256 + kc * 32 + kq * 8;
#pragma unroll
        for (int j = 0; j < 8; ++j) v[j] = (__bf16)(src[j] * scale);
    } else {
        int g = f - 24;
#pragma unroll
        for (int j = 0; j < 8; ++j) {
            int k = kq * 8 + j;
            float val = 0.f;
            if (k < 6) {
                val = (g == 0) ? Gtab[k * 768 + col]
                    : (g == 1) ? Gtab[k * 768 + 256 + col]
                    : (g == 2) ? b_hh[512 + col] * TWO_LOG2E_F
                               : Gtab[k * 768 + 512 + col];
            }
            v[j] = (__bf16)val;
        }
    }
    *(bf16x8*)(Wg + (size_t)u * 8) = v;
}

// ---------------- K3: main recurrent kernel ----------------
__global__ __launch_bounds__(512) void k_main(
    const float* __restrict__ latent, const int* __restrict__ tgt,
    const __bf16* __restrict__ Wg, const float* __restrict__ Wout,
    const float* __restrict__ bout, float* __restrict__ out) {

    __shared__ __bf16 h_lds[8][8][64][8];     // [tile][kc][slot][j] : 64 KB, single-buf
    __shared__ __bf16 woutf_lds[8][64][8];    // W_out A-frags : 8 KB
    __shared__ int    tok_lds[128 * 9];       // 4.5 KB, padded stride 9
    __shared__ float  logit_lds[128 * 40];    // 20 KB

    const int tid   = threadIdx.x;
    const int lane  = tid & 63;
    const int u     = tid >> 6;      // wave 0..7
    const int group = u >> 2;        // 0 = P (tiles 0-3), 1 = Q (tiles 4-7)
    const int gu    = u & 3;         // wave-in-group: col-slices 4gu..4gu+3
    const int q     = lane >> 4;     // k-quad / C row-quad
    const int n16   = lane & 15;     // batch row within 16-row tile
    const int row0  = blockIdx.x * 128;
    const int Tl    = group * 4 + gu;   // this wave's logit tile

    // ---- stage W_out A-frags (8 kc x 64 lanes == 512 threads) ----
    {
        int kc = tid >> 6, ln = tid & 63, m = ln & 15, kq2 = ln >> 4;
        bf16x8 v;
#pragma unroll
        for (int j = 0; j < 8; ++j)
            v[j] = (m < 5) ? (__bf16)Wout[m * 256 + kc * 32 + kq2 * 8 + j] : (__bf16)0.f;
        *(bf16x8*)&woutf_lds[kc][ln][0] = v;
    }
    // ---- tokens: 128 rows x 8 steps ----
    for (int i = tid; i < 1024; i += 512) {
        int r = i >> 3, t = i & 7;
        tok_lds[r * 9 + t] = (t == 0) ? 5 : tgt[(size_t)(row0 + r) * 8 + t - 1];
    }
    // ---- init h (bf16, frag-linear): 128 rows x 256 cols ----
    for (int i = tid; i < 128 * 64; i += 512) {
        int r = i >> 6, cq = i & 63, c = cq * 4;
        float4 hv = *(const float4*)(latent + (size_t)(row0 + r) * 256 + c);
        bf16x4 hb;
        hb[0] = (__bf16)hv.x; hb[1] = (__bf16)hv.y;
        hb[2] = (__bf16)hv.z; hb[3] = (__bf16)hv.w;
        *(bf16x4*)&h_lds[r >> 4][c >> 5][(r & 15) + 16 * ((c >> 3) & 3)][c & 7] = hb;
    }
    const float bo0 = bout[0], bo1 = bout[1], bo2 = bout[2], bo3 = bout[3], bo4 = bout[4];
    const f32x4 z4 = {0.f, 0.f, 0.f, 0.f};

    f32x4 acc[3][4][4];   // [gate][ct][nt] = 192 VGPRs
    __syncthreads();

    // ---- 17 staggered phases: P MFMAs on even ph, Q on odd ----
    for (int ph = 0; ph < 17; ++ph) {
        if (((ph ^ group) & 1) == 0) {
            const int t = (ph - group) >> 1;
            if (t < 8) {
                __builtin_amdgcn_s_setprio(1);
                // ---- MFMA phase: stream W, acc[g][ct][nt] (kc=0 peeled, C=z4) ----
                {
                    bf16x8 b0 = *(const bf16x8*)&h_lds[group * 4 + 0][0][lane][0];
                    bf16x8 b1 = *(const bf16x8*)&h_lds[group * 4 + 1][0][lane][0];
                    bf16x8 b2 = *(const bf16x8*)&h_lds[group * 4 + 2][0][lane][0];
                    bf16x8 b3 = *(const bf16x8*)&h_lds[group * 4 + 3][0][lane][0];
#pragma unroll
                    for (int g = 0; g < 3; ++g)
#pragma unroll
                        for (int ct = 0; ct < 4; ++ct) {
                            bf16x8 a = *(const bf16x8*)(Wg +
                                (size_t)((4 * gu + ct) * 28 + g * 8) * 512 + lane * 8);
                            acc[g][ct][0] = MFMA16(a, b0, z4);
                            acc[g][ct][1] = MFMA16(a, b1, z4);
                            acc[g][ct][2] = MFMA16(a, b2, z4);
                            acc[g][ct][3] = MFMA16(a, b3, z4);
                        }
                }
#pragma unroll 1
                for (int kc = 1; kc < 8; ++kc) {
                    bf16x8 b0 = *(const bf16x8*)&h_lds[group * 4 + 0][kc][lane][0];
                    bf16x8 b1 = *(const bf16x8*)&h_lds[group * 4 + 1][kc][lane][0];
                    bf16x8 b2 = *(const bf16x8*)&h_lds[group * 4 + 2][kc][lane][0];
                    bf16x8 b3 = *(const bf16x8*)&h_lds[group * 4 + 3][kc][lane][0];
#pragma unroll
                    for (int g = 0; g < 3; ++g)
#pragma unroll
                        for (int ct = 0; ct < 4; ++ct) {
                            bf16x8 a = *(const bf16x8*)(Wg +
                                (size_t)((4 * gu + ct) * 28 + g * 8 + kc) * 512 + lane * 8);
                            acc[g][ct][0] = MFMA16(a, b0, acc[g][ct][0]);
                            acc[g][ct][1] = MFMA16(a, b1, acc[g][ct][1]);
                            acc[g][ct][2] = MFMA16(a, b2, acc[g][ct][2]);
                            acc[g][ct][3] = MFMA16(a, b3, acc[g][ct][3]);
                        }
                }
                // ---- logit MFMA for step t-1 (h_t is stable this phase) ----
                if (t > 0) {
                    f32x4 lacc = z4;
#pragma unroll
                    for (int kc = 0; kc < 8; ++kc) {
                        bf16x8 wf = *(const bf16x8*)&woutf_lds[kc][lane][0];
                        bf16x8 bb = *(const bf16x8*)&h_lds[Tl][kc][lane][0];
                        lacc = MFMA16(wf, bb, lacc);
                    }
                    float* dst = &logit_lds[(Tl * 16 + n16) * 40 + (t - 1) * 5];
                    if (q == 0) {
                        dst[0] = lacc[0] + bo0; dst[1] = lacc[1] + bo1;
                        dst[2] = lacc[2] + bo2; dst[3] = lacc[3] + bo3;
                    } else if (q == 1) {
                        dst[4] = lacc[0] + bo4;
                    }
                }
                __builtin_amdgcn_s_setprio(0);
            }
        } else {
            const int tc = (ph - group - 1) >> 1;
            if (tc >= 0 && tc < 8) {
                // ---- combine phase: one-hot/bias MFMAs + GRU VALU ----
                bf16x8 oh[4];
#pragma unroll
                for (int nt = 0; nt < 4; ++nt) {
                    int tokv = tok_lds[((group * 4 + nt) * 16 + n16) * 9 + tc];
                    u16x8 o;
#pragma unroll
                    for (int j = 0; j < 8; ++j)
                        o[j] = (q * 8 + j == tokv) ? (unsigned short)0x3F80 : (unsigned short)0;
                    oh[nt] = __builtin_bit_cast(bf16x8, o);
                }
#pragma unroll
                for (int ct = 0; ct < 4; ++ct) {
                    const __bf16* ob = Wg + (size_t)((4 * gu + ct) * 28 + 24) * 512 + lane * 8;
                    bf16x8 a0 = *(const bf16x8*)(ob);
                    bf16x8 a1 = *(const bf16x8*)(ob + 512);
                    bf16x8 a2 = *(const bf16x8*)(ob + 1024);
                    bf16x8 a3 = *(const bf16x8*)(ob + 1536);
                    const int cb  = 64 * gu + 16 * ct + 4 * q;
                    const int kch = cb >> 5;
                    const int sl  = n16 + 16 * ((cb >> 3) & 3);
                    const int j0  = cb & 7;
#pragma unroll
                    for (int nt = 0; nt < 4; ++nt) {
                        f32x4 ar = MFMA16(a0, oh[nt], acc[0][ct][nt]);   // r-pre
                        f32x4 az = MFMA16(a1, oh[nt], acc[1][ct][nt]);   // z-pre
                        f32x4 an = MFMA16(a2, oh[nt], acc[2][ct][nt]);   // Whn.h+bhn
                        f32x4 ai = MFMA16(a3, oh[nt], z4);               // i_n
                        bf16x4* slot = (bf16x4*)&h_lds[group * 4 + nt][kch][sl][j0];
                        bf16x4 hold = *slot;
                        bf16x4 hb;
#pragma unroll
                        for (int i = 0; i < 4; ++i) {
                            float rg = sigm2(ar[i]);
                            float zg = sigm2(az[i]);
                            float ng = tanh2(__builtin_fmaf(rg, an[i], ai[i]));
                            float hv = ng + zg * ((float)hold[i] - ng);
                            hb[i] = (__bf16)hv;
                        }
                        *slot = hb;
                    }
                }
            }
        }
        lds_barrier();
    }

    // ---- epilogue: logits for step 7 from final h ----
    {
        f32x4 lacc = z4;
#pragma unroll
        for (int kc = 0; kc < 8; ++kc) {
            bf16x8 wf = *(const bf16x8*)&woutf_lds[kc][lane][0];
            bf16x8 bb = *(const bf16x8*)&h_lds[Tl][kc][lane][0];
            lacc = MFMA16(wf, bb, lacc);
        }
        float* dst = &logit_lds[(Tl * 16 + n16) * 40 + 7 * 5];
        if (q == 0) {
            dst[0] = lacc[0] + bo0; dst[1] = lacc[1] + bo1;
            dst[2] = lacc[2] + bo2; dst[3] = lacc[3] + bo3;
        } else if (q == 1) {
            dst[4] = lacc[0] + bo4;
        }
    }
    __syncthreads();
    // ---- coalesced output dump: 128 rows x 40 floats ----
    for (int i = tid; i < 128 * 40; i += 512)
        out[(size_t)row0 * 40 + i] = logit_lds[i];
}

extern "C" void kernel_launch(void* const* d_in, const int* in_sizes, int n_in,
                              void* d_out, int out_size, void* d_ws, size_t ws_size,
                              hipStream_t stream) {
    const float* latent = (const float*)d_in[0];
    const int*   tgt    = (const int*)d_in[1];
    const float* emb    = (const float*)d_in[2];
    const float* W_ih   = (const float*)d_in[3];
    const float* W_hh   = (const float*)d_in[4];
    const float* b_ih   = (const float*)d_in[5];
    const float* b_hh   = (const float*)d_in[6];
    const float* W_out  = (const float*)d_in[7];
    const float* b_out  = (const float*)d_in[8];
    float* out = (float*)d_out;

    float*  Gtab = (float*)d_ws;                       // 6*768*4 = 18432 B
    __bf16* Wg   = (__bf16*)((char*)d_ws + 18432);     // 448 frags*512*2 = 458752 B

    k_gtable<<<6, 768, 0, stream>>>(emb, W_ih, b_ih, b_hh, Gtab);
    k_wfrag3<<<112, 256, 0, stream>>>(W_hh, Gtab, b_hh, Wg);
    k_main<<<512, 512, 0, stream>>>(latent, tgt, Wg, W_out, b_out, out);
}

// Round 13
// 250.656 us; speedup vs baseline: 2.3447x; 2.3447x over previous
//
#include <hip/hip_runtime.h>
#include <hip/hip_bf16.h>

// AutoregressiveRoutingHead: B=65536, L=8, LATENT=256, HID=128, NTOK=5
//  K1: G[tok][j] = (emb@W_ih + b_ih (+b_hh)) * scale  (exp2-prescaled, 6x768)
//  K2: augmented W -> bf16 frag-linear Wg for mfma_f32_16x16x32_bf16:
//      slice w (cols 16w..+16): f=g*8+kc (g<3,kc<8) = W_hh*scale_g;
//      f=24+g = one-hot K-block (i_r,i_z,bhn,i_n in k-cols 0..5).
//  K3 (r13 = r10 + LDS-staged one-hot W-block):
//      1024 blocks x 1024 threads (16 waves, 4/SIMD, 128-reg cap). Wave w owns
//      gate-cols [16w,16w+16) across all 4 N-tiles; acc[4][4] f32x4 = 64 regs.
//      The step-invariant one-hot A-frags (f24..27, 64 KB/block) are staged in
//      LDS once -> W L2 stream drops 448->384 KB/block-step. One-hot B-table
//      compacted to kq=0 lanes only ([8][4][16][8], 8 KB) + cndmask for q>0
//      (bit-exact: tok<=5<8 so kq>0 frags are all-zero). Combine = exp2-form
//      GRU, hold from LDS. h bf16 dbuf, ONE lgkm-only barrier/step. Logits
//      via MFMA on waves 0/5/10/15, skewed one step. setprio(1) on MFMA phase.

typedef __attribute__((ext_vector_type(8)))  __bf16 bf16x8;
typedef __attribute__((ext_vector_type(4)))  __bf16 bf16x4;
typedef __attribute__((ext_vector_type(8)))  unsigned short u16x8;
typedef __attribute__((ext_vector_type(4)))  float  f32x4;

#define LOG2E_F     1.4426950408889634f
#define TWO_LOG2E_F 2.8853900817779268f

#if __has_builtin(__builtin_amdgcn_exp2f)
#define EXP2F(x) __builtin_amdgcn_exp2f(x)
#else
#define EXP2F(x) __expf((x) * 0.6931471805599453f)
#endif

__device__ __forceinline__ float sigm2(float a) {   // sigmoid, arg pre-scaled by log2e
    return __builtin_amdgcn_rcpf(1.f + EXP2F(-a));
}
__device__ __forceinline__ float tanh2(float a) {   // tanh, arg pre-scaled by 2log2e
    return __builtin_fmaf(2.f, __builtin_amdgcn_rcpf(1.f + EXP2F(-a)), -1.f);
}
__device__ __forceinline__ void lds_barrier() {
    __builtin_amdgcn_sched_barrier(0);
    asm volatile("s_waitcnt lgkmcnt(0)" ::: "memory");
    __builtin_amdgcn_s_barrier();
    __builtin_amdgcn_sched_barrier(0);
}

#define MFMA16(a, b, c) __builtin_amdgcn_mfma_f32_16x16x32_bf16((a), (b), (c), 0, 0, 0)

// ---------------- K1: gi table (exp2-pre-scaled) ----------------
__global__ void k_gtable(const float* __restrict__ emb, const float* __restrict__ W_ih,
                         const float* __restrict__ b_ih, const float* __restrict__ b_hh,
                         float* __restrict__ G) {
    int tok = blockIdx.x;      // 0..5
    int j   = threadIdx.x;     // 0..767
    const float4* e4 = (const float4*)(emb + tok * 128);
    const float4* w4 = (const float4*)(W_ih + (size_t)j * 128);
    float s = 0.f;
#pragma unroll
    for (int k = 0; k < 32; ++k) {
        float4 a = e4[k], b = w4[k];
        s += a.x * b.x + a.y * b.y + a.z * b.z + a.w * b.w;
    }
    s += b_ih[j];
    if (j < 512) s = (s + b_hh[j]) * LOG2E_F;   // r,z rows
    else         s = s * TWO_LOG2E_F;           // i_n rows
    G[tok * 768 + j] = s;
}

// ---------------- K2: augmented W -> 16x16x32 A-frags (pre-scaled) --------
// Frag layout: lane = m + 16*kq (m=0..15, kq=0..3), elem j -> k = kq*8+j.
__global__ void k_wfrag3(const float* __restrict__ Whh, const float* __restrict__ Gtab,
                         const float* __restrict__ b_hh, __bf16* __restrict__ Wg) {
    int u    = blockIdx.x * 256 + threadIdx.x;   // 0..28671 (448 frags x 64 lanes)
    int lane = u & 63;
    int frag = u >> 6;            // 0..447
    int w    = frag / 28;
    int f    = frag - 28 * w;     // 0..27
    int col  = w * 16 + (lane & 15);
    int kq   = lane >> 4;
    bf16x8 v;
    if (f < 24) {
        int g = f >> 3, kc = f & 7;
        float scale = (g < 2) ? LOG2E_F : TWO_LOG2E_F;
        const float* src = Whh + (size_t)(g * 256 + col) * 256 + kc * 32 + kq * 8;
#pragma unroll
        for (int j = 0; j < 8; ++j) v[j] = (__bf16)(src[j] * scale);
    } else {
        int g = f - 24;
#pragma unroll
        for (int j = 0; j < 8; ++j) {
            int k = kq * 8 + j;
            float val = 0.f;
            if (k < 6) {
                val = (g == 0) ? Gtab[k * 768 + col]
                    : (g == 1) ? Gtab[k * 768 + 256 + col]
                    : (g == 2) ? b_hh[512 + col] * TWO_LOG2E_F
                               : Gtab[k * 768 + 512 + col];
            }
            v[j] = (__bf16)val;
        }
    }
    *(bf16x8*)(Wg + (size_t)u * 8) = v;
}

// ---------------- K3: main recurrent kernel ----------------
__global__ __launch_bounds__(1024) void k_main(
    const float* __restrict__ latent, const int* __restrict__ tgt,
    const __bf16* __restrict__ Wg, const float* __restrict__ Wout,
    const float* __restrict__ bout, float* __restrict__ out) {

    __shared__ __bf16 h_lds[2][4][8][64][8];    // [buf][nt][kc][lane][j] : 64 KB
    __shared__ __bf16 ohc_lds[8][4][16][8];     // compact one-hot (kq=0 rows) : 8 KB
    __shared__ __bf16 wstage_lds[16][4][64][8]; // one-hot A-frags f24..27 : 64 KB
    __shared__ __bf16 woutf_lds[8][64][8];      // W_out A-frags : 8 KB
    __shared__ float  logit_lds[64 * 40];       // logits : 10 KB   (total ~154 KB)

    const int tid  = threadIdx.x;
    const int lane = tid & 63;
    const int w    = tid >> 6;       // wave 0..15 : gate-col slice [16w,16w+16)
    const int q    = lane >> 4;      // k-quad within frag / row-quad in C
    const int n16  = lane & 15;      // batch index within 16-row N-tile
    const int row0 = blockIdx.x * 64;

    // per-thread A-frag base; local frag f at wbase + f*512 elements
    const __bf16* wbase = Wg + ((size_t)(w * 28) * 64 + lane) * 8;

    // combine-element <-> B-frag LDS mapping:
    // element (nt, col=16w+4q+i): kc_h=w>>1, lane'=n16+16*((2w+(q>>1))&3), j=4*(q&1)+i
    const int kc_h  = w >> 1;
    const int slotl = n16 + 16 * ((2 * w + (q >> 1)) & 3);
    const int joff  = 4 * (q & 1);

    // ---- stage W_out A-frags (16 rows, 5 used) ----
    if (tid < 512) {
        int kc = tid >> 6, ln = tid & 63, m = ln & 15, kq2 = ln >> 4;
        bf16x8 v;
#pragma unroll
        for (int j = 0; j < 8; ++j)
            v[j] = (m < 5) ? (__bf16)Wout[m * 256 + kc * 32 + kq2 * 8 + j] : (__bf16)0.f;
        *(bf16x8*)&woutf_lds[kc][ln][0] = v;
    }
    // ---- compact one-hot B-table: [t][nt][n16] (kq=0 lanes only) ----
    if (tid < 512) {
        int t = tid >> 6, nt = (tid >> 4) & 3, nn = tid & 15;
        int tok = (t == 0) ? 5 : tgt[(size_t)(row0 + nt * 16 + nn) * 8 + t - 1];
        u16x8 o;
#pragma unroll
        for (int j = 0; j < 8; ++j) o[j] = (j == tok) ? (unsigned short)0x3F80 : (unsigned short)0;
        *(u16x8*)&ohc_lds[t][nt][nn][0] = o;
    }
    // ---- stage the step-invariant one-hot A-frags (f24..27, all slices) ----
    for (int idx = tid; idx < 4096; idx += 1024) {
        int ws = idx >> 8, f = (idx >> 6) & 3, ln = idx & 63;
        bf16x8 v = *(const bf16x8*)(Wg + ((size_t)(ws * 28 + 24 + f) * 64 + ln) * 8);
        *(bf16x8*)&wstage_lds[ws][f][ln][0] = v;
    }
    // ---- init h in LDS buf 0 (bf16) ----
#pragma unroll
    for (int nt = 0; nt < 4; ++nt) {
        float4 hv = *(const float4*)(latent + (size_t)(row0 + nt * 16 + n16) * 256 + 16 * w + 4 * q);
        bf16x4 hb;
        hb[0] = (__bf16)hv.x; hb[1] = (__bf16)hv.y;
        hb[2] = (__bf16)hv.z; hb[3] = (__bf16)hv.w;
        *(bf16x4*)&h_lds[0][nt][kc_h][slotl][joff] = hb;
    }
    // logit-wave assignment: one per SIMD (waves 0,5,10,15 -> nt 0..3)
    const int lw = (w == 0) ? 0 : (w == 5) ? 1 : (w == 10) ? 2 : (w == 15) ? 3 : -1;
    const float bo0 = bout[0], bo1 = bout[1], bo2 = bout[2], bo3 = bout[3], bo4 = bout[4];
    const f32x4 z4 = {0.f, 0.f, 0.f, 0.f};
    const bf16x8 zoh = __builtin_bit_cast(bf16x8, (u16x8){0, 0, 0, 0, 0, 0, 0, 0});
    __syncthreads();

    for (int t = 0; t < 8; ++t) {
        const int cur = t & 1, nxt = cur ^ 1;
        f32x4 acc[4][4];   // [gate][nt]; initialized by one-hot MFMAs (C=z4)

        __builtin_amdgcn_s_setprio(1);
        // ---- one-hot K-block FIRST (A from LDS wstage, B compact+masked):
        //      delivers i_r,i_z into acc0/1, bhn into acc2, i_n into acc3 ----
        {
            bf16x8 a0 = *(const bf16x8*)&wstage_lds[w][0][lane][0];
            bf16x8 a1 = *(const bf16x8*)&wstage_lds[w][1][lane][0];
            bf16x8 a2 = *(const bf16x8*)&wstage_lds[w][2][lane][0];
            bf16x8 a3 = *(const bf16x8*)&wstage_lds[w][3][lane][0];
#pragma unroll
            for (int nt = 0; nt < 4; ++nt) {
                bf16x8 ov = *(const bf16x8*)&ohc_lds[t][nt][n16][0];
                bf16x8 oh = (q == 0) ? ov : zoh;   // kq>0 one-hot rows are zero
                acc[0][nt] = MFMA16(a0, oh, z4);
                acc[1][nt] = MFMA16(a1, oh, z4);
                acc[2][nt] = MFMA16(a2, oh, z4);
                acc[3][nt] = MFMA16(a3, oh, z4);
            }
        }
        // ---- stream kc 0..7 from L2 (each frag loaded by exactly one wave) ----
#pragma unroll 2
        for (int kc = 0; kc < 8; ++kc) {
            bf16x8 a0 = *(const bf16x8*)(wbase + (size_t)kc * 512);
            bf16x8 a1 = *(const bf16x8*)(wbase + (size_t)(8 + kc) * 512);
            bf16x8 a2 = *(const bf16x8*)(wbase + (size_t)(16 + kc) * 512);
#pragma unroll
            for (int nt = 0; nt < 4; ++nt) {
                bf16x8 bb = *(const bf16x8*)&h_lds[cur][nt][kc][lane][0];
                acc[0][nt] = MFMA16(a0, bb, acc[0][nt]);
                acc[1][nt] = MFMA16(a1, bb, acc[1][nt]);
                acc[2][nt] = MFMA16(a2, bb, acc[2][nt]);
            }
        }

        // ---- logit MFMA (skewed one step), one wave per SIMD ----
        if (lw >= 0 && t > 0) {
            f32x4 lacc = z4;
#pragma unroll
            for (int kc = 0; kc < 8; ++kc) {
                bf16x8 wf = *(const bf16x8*)&woutf_lds[kc][lane][0];
                bf16x8 bb = *(const bf16x8*)&h_lds[cur][lw][kc][lane][0];
                lacc = MFMA16(wf, bb, lacc);
            }
            // C: batch = lane&15, o = q*4 + i
            float* dst = &logit_lds[(lw * 16 + n16) * 40 + (t - 1) * 5];
            if (q == 0) {
                dst[0] = lacc[0] + bo0; dst[1] = lacc[1] + bo1;
                dst[2] = lacc[2] + bo2; dst[3] = lacc[3] + bo3;
            } else if (q == 1) {
                dst[4] = lacc[0] + bo4;
            }
        }
        __builtin_amdgcn_s_setprio(0);

        // ---- combine: GRU update, exp2-form (no muls), hold from LDS ----
#pragma unroll
        for (int nt = 0; nt < 4; ++nt) {
            bf16x4 hold = *(const bf16x4*)&h_lds[cur][nt][kc_h][slotl][joff];
            bf16x4 hb;
#pragma unroll
            for (int i = 0; i < 4; ++i) {
                float rg = sigm2(acc[0][nt][i]);
                float zg = sigm2(acc[1][nt][i]);
                float ng = tanh2(__builtin_fmaf(rg, acc[2][nt][i], acc[3][nt][i]));
                float hv = ng + zg * ((float)hold[i] - ng);
                hb[i] = (__bf16)hv;
            }
            *(bf16x4*)&h_lds[nxt][nt][kc_h][slotl][joff] = hb;
        }
        lds_barrier();   // h_lds[nxt] published; one barrier per step
    }

    // ---- epilogue: logits for step 7 from final h (buf 0 after t=7) ----
    if (lw >= 0) {
        f32x4 lacc = z4;
#pragma unroll
        for (int kc = 0; kc < 8; ++kc) {
            bf16x8 wf = *(const bf16x8*)&woutf_lds[kc][lane][0];
            bf16x8 bb = *(const bf16x8*)&h_lds[0][lw][kc][lane][0];
            lacc = MFMA16(wf, bb, lacc);
        }
        float* dst = &logit_lds[(lw * 16 + n16) * 40 + 7 * 5];
        if (q == 0) {
            dst[0] = lacc[0] + bo0; dst[1] = lacc[1] + bo1;
            dst[2] = lacc[2] + bo2; dst[3] = lacc[3] + bo3;
        } else if (q == 1) {
            dst[4] = lacc[0] + bo4;
        }
    }
    __syncthreads();
    // ---- coalesced output dump: 64 rows x (8 t x 5 o) contiguous ----
    for (int i = tid; i < 64 * 40; i += 1024)
        out[(size_t)row0 * 40 + i] = logit_lds[i];
}

extern "C" void kernel_launch(void* const* d_in, const int* in_sizes, int n_in,
                              void* d_out, int out_size, void* d_ws, size_t ws_size,
                              hipStream_t stream) {
    const float* latent = (const float*)d_in[0];
    const int*   tgt    = (const int*)d_in[1];
    const float* emb    = (const float*)d_in[2];
    const float* W_ih   = (const float*)d_in[3];
    const float* W_hh   = (const float*)d_in[4];
    const float* b_ih   = (const float*)d_in[5];
    const float* b_hh   = (const float*)d_in[6];
    const float* W_out  = (const float*)d_in[7];
    const float* b_out  = (const float*)d_in[8];
    float* out = (float*)d_out;

    float*  Gtab = (float*)d_ws;                       // 6*768*4 = 18432 B
    __bf16* Wg   = (__bf16*)((char*)d_ws + 18432);     // 448 frags*512*2 = 458752 B

    k_gtable<<<6, 768, 0, stream>>>(emb, W_ih, b_ih, b_hh, Gtab);
    k_wfrag3<<<112, 256, 0, stream>>>(W_hh, Gtab, b_hh, Wg);
    k_main<<<1024, 1024, 0, stream>>>(latent, tgt, Wg, W_out, b_out, out);
}